// Round 7
// baseline (1951.879 us; speedup 1.0000x reference)
//
#include <hip/hip_runtime.h>
#include <hip/hip_bf16.h>

// Problem constants
#define Tt   50
#define Dd   64
#define NOUT 100
#define G4   512   // 4*H
#define K0S  72    // a0 LDS stride in shorts (64 x-cols + 8 pad; 144B = 16B-aligned)
#define K1P  264   // a1 LDS stride in shorts (256 + 8 pad; 528B = 16B-aligned)
#define BM   16    // batch rows per workgroup (grid 256 = 4096/16)

typedef __attribute__((ext_vector_type(8))) short  short8;
typedef __attribute__((ext_vector_type(4))) float  floatx4;

#if __has_builtin(__builtin_amdgcn_exp2f)
#define EXP2(v) __builtin_amdgcn_exp2f(v)
#else
#define EXP2(v) exp2f(v)
#endif
__device__ __forceinline__ float rcp_(float v) { return __builtin_amdgcn_rcpf(v); }
#define KN2L2E (-2.8853900817779268f)   // -2*log2(e): tanh(c) on natural-units c

__device__ __forceinline__ short f2bf(float f) {
    __hip_bfloat16 h = __float2bfloat16(f);
    return *reinterpret_cast<const short*>(&h);
}

// ws layout (bytes):
//  w0f bf16[ 98304] @ 0        (layer0 [Wk0;Wr0] 192x512, frag f=nt*6+kt, nt=w+8g, PRESCALED)
//  w1f bf16[131072] @ 196608   (layer1 [Wk1;Wr1] 256x512, frag f=nt*8+kt, PRESCALED)
//  wdf bf16[  8192] @ 458752   (Wd 128x64, frag f=nt*4+kt, unscaled)
//  b0f f32[512]     @ 475136   (PRESCALED, warm path)
//  b1f f32[512]     @ 477184   (PRESCALED)
//  bdf f32[64]      @ 479232   (unscaled)
//  wff bf16[ 65536] @ 479488   (Wf = Wd@Wk0, 128x512, frag f=nt*4+kt, PRESCALED)
//  b0a f32[512]     @ 610560   (sc*(b0 + bd@Wk0), AR path)
#define W1F_OFF 196608
#define WDF_OFF 458752
#define B0F_OFF 475136
#define B1F_OFF 477184
#define BDF_OFF 479232
#define WFF_OFF 479488
#define B0A_OFF 610560

__global__ __launch_bounds__(256) void prep_kernel(
    const float* __restrict__ Wk0, const float* __restrict__ Wr0, const float* __restrict__ b0,
    const float* __restrict__ Wk1, const float* __restrict__ Wr1, const float* __restrict__ b1,
    const float* __restrict__ Wd,  const float* __restrict__ bd,  char* __restrict__ ws)
{
    int idx = blockIdx.x * 256 + threadIdx.x;
    short* w0f = (short*)ws;
    short* w1f = (short*)(ws + W1F_OFF);
    short* wdf = (short*)(ws + WDF_OFF);
    float* b0f = (float*)(ws + B0F_OFF);
    float* b1f = (float*)(ws + B1F_OFF);
    float* bdf = (float*)(ws + BDF_OFF);
    short* wff = (short*)(ws + WFF_OFF);
    float* b0a = (float*)(ws + B0A_OFF);
    const float NL2E  = -1.4426950408889634f;   // -log2(e): i,f,o (sigmoid)
    const float N2L2E = -2.8853900817779268f;   // -2log2(e): g (tanh)

    if (idx < 98304) {
        int f = idx >> 9, r = idx & 511;
        int lane = r >> 3, j = r & 7;
        int nt = f / 6, kt = f - nt * 6;
        int k = kt * 32 + (lane >> 4) * 8 + j;
        int col = nt * 16 + (lane & 15);
        float sc = ((col >> 7) == 2) ? N2L2E : NL2E;
        w0f[idx] = f2bf(sc * ((k < Dd) ? Wk0[k * G4 + col] : Wr0[(k - Dd) * G4 + col]));
    } else if (idx < 229376) {
        int i2 = idx - 98304;
        int f = i2 >> 9, r = i2 & 511;
        int lane = r >> 3, j = r & 7;
        int nt = f >> 3, kt = f & 7;
        int k = kt * 32 + (lane >> 4) * 8 + j;
        int col = nt * 16 + (lane & 15);
        float sc = ((col >> 7) == 2) ? N2L2E : NL2E;
        w1f[i2] = f2bf(sc * ((k < 128) ? Wk1[k * G4 + col] : Wr1[(k - 128) * G4 + col]));
    } else if (idx < 237568) {
        int i2 = idx - 229376;
        int f = i2 >> 9, r = i2 & 511;
        int lane = r >> 3, j = r & 7;
        int nt = f >> 2, kt = f & 3;
        int k = kt * 32 + (lane >> 4) * 8 + j;
        int col = nt * 16 + (lane & 15);
        wdf[i2] = f2bf(Wd[k * Dd + col]);
    } else if (idx < 238656) {
        int i2 = idx - 237568;
        if (i2 < 512) {
            float sc = ((i2 >> 7) == 2) ? N2L2E : NL2E;
            b0f[i2] = sc * b0[i2];
        } else if (i2 < 1024) {
            int c = i2 - 512;
            float sc = ((c >> 7) == 2) ? N2L2E : NL2E;
            b1f[c] = sc * b1[c];
        } else if (i2 < 1088) bdf[i2 - 1024] = bd[i2 - 1024];
    } else if (idx < 304192) {
        // Wf = Wd @ Wk0 (fused AR layer-0 weights), prescaled, frag-ordered
        int i3 = idx - 238656;
        int f = i3 >> 9, r = i3 & 511;
        int lane = r >> 3, j = r & 7;
        int nt = f >> 2, kt = f & 3;
        int k = kt * 32 + (lane >> 4) * 8 + j;     // hidden index 0..127
        int col = nt * 16 + (lane & 15);           // z0 col 0..511
        float sc = ((col >> 7) == 2) ? N2L2E : NL2E;
        float acc = 0.f;
        for (int d = 0; d < Dd; ++d)
            acc = fmaf(Wd[k * Dd + d], Wk0[d * G4 + col], acc);
        wff[i3] = f2bf(sc * acc);
    } else if (idx < 304704) {
        int n = idx - 304192;
        float sc = ((n >> 7) == 2) ? N2L2E : NL2E;
        float acc = b0[n];
        for (int d = 0; d < Dd; ++d)
            acc = fmaf(bd[d], Wk0[d * G4 + n], acc);
        b0a[n] = sc * acc;
    }
}

// Dynamic LDS layout (bytes):
//  a0[2] @ 0     : 2 × 16*72*2  = 4608   (x tiles, ping-pong; warm only)
//  a1[2] @ 4608  : 2 × 16*264*2 = 16896  (h0 | h1 tiles, ping-pong)
//  w0l   @ 21504 : 131072                (W0 pairs p=0..15, [p][wave][512])
#define SM_A1  4608
#define SM_W0  21504
#define SM_TOT 152576
#define A0SZ   1152   // shorts per a0 buffer
#define A1SZ   4224   // shorts per a1 buffer

// grid 256, block 512 (8 waves), 1 block/CU. Wave w owns hidden cols 16w..16w+15.
// All weights CU-resident. AR dense head FUSED into layer 0 via Wf = Wd@Wk0:
// pred never touches LDS, output-dense computed lazily (off critical path).
// Warm step = 1 barrier, AR step = 2 barriers.
__global__ __launch_bounds__(512, 2) void lstm_kernel(
    const float* __restrict__ x, const char* __restrict__ ws, float* __restrict__ out)
{
    extern __shared__ char smem[];
    short* a0b = (short*)smem;
    short* a1b = (short*)(smem + SM_A1);
    short* w0l = (short*)(smem + SM_W0);

    const short* w0f = (const short*)ws;
    const short* w1f = (const short*)(ws + W1F_OFF);
    const short* wdf = (const short*)(ws + WDF_OFF);
    const float* b0f = (const float*)(ws + B0F_OFF);
    const float* b1f = (const float*)(ws + B1F_OFF);
    const float* bdf = (const float*)(ws + BDF_OFF);
    const short* wff = (const short*)(ws + WFF_OFF);
    const float* b0a = (const float*)(ws + B0A_OFF);

    const int tid  = threadIdx.x;
    const int w    = tid >> 6;
    const int lane = tid & 63;
    const int l15  = lane & 15;
    const int quad = lane >> 4;
    const int row0 = blockIdx.x * BM;

    // ---- one-time staging ----
    for (int i = tid; i < 2 * A1SZ; i += 512) a1b[i] = 0;
    for (int c = tid; c < 8192; c += 512) {       // W0 pairs p<16 -> LDS
        int e8 = c & 63;
        int wv = (c >> 6) & 7;
        int p  = c >> 9;
        int g = p / 6, kt = p - g * 6;
        const short* src = w0f + ((((g * 8 + wv) * 6) + kt) << 9) + e8 * 8;
        *(short8*)&w0l[((p * 8 + wv) << 9) + e8 * 8] = *(const short8*)src;
    }
    {   // stage x_0 -> a0[0]
        int colx = tid & 63, rg = tid >> 6;
        a0b[rg * K0S + colx]       = f2bf(x[(size_t)(row0 + rg) * (Tt * Dd) + colx]);
        a0b[(rg + 8) * K0S + colx] = f2bf(x[(size_t)(row0 + rg + 8) * (Tt * Dd) + colx]);
    }

    // register-resident weights
    const short* w0rb = w0f + w * 3072 + lane * 8;
    const short* w1rb = w1f + w * 4096 + lane * 8;
    short8 W1R[4][8];
    #pragma unroll
    for (int g = 0; g < 4; ++g)
        #pragma unroll
        for (int kt = 0; kt < 8; ++kt)
            W1R[g][kt] = *(const short8*)(w1rb + g * 32768 + kt * 512);
    short8 W0R[8];   // W0 pairs p = 16..23
    #pragma unroll
    for (int p = 16; p < 24; ++p) {
        int g = p / 6, kt = p - g * 6;
        W0R[p - 16] = *(const short8*)(w0rb + g * 24576 + kt * 512);
    }
    short8 WfR[16];  // fused AR-L0 weights, frag f = (w+8g)*4 + kt
    #pragma unroll
    for (int g = 0; g < 4; ++g)
        #pragma unroll
        for (int kt = 0; kt < 4; ++kt)
            WfR[g * 4 + kt] = *(const short8*)(wff + (((w + 8 * g) * 4 + kt) << 9) + lane * 8);
    short8 WdR[4];
    if (w < 4) {
        #pragma unroll
        for (int kt = 0; kt < 4; ++kt)
            WdR[kt] = *(const short8*)(wdf + ((w * 4 + kt) << 9) + lane * 8);
    }

    const int hu = w * 16 + l15;
    const float bi0 = b0f[hu], bff0 = b0f[128 + hu], bg0 = b0f[256 + hu], bo0 = b0f[384 + hu];
    const float bi1 = b1f[hu], bff1 = b1f[128 + hu], bg1 = b1f[256 + hu], bo1 = b1f[384 + hu];
    const float bia = b0a[hu], bfa = b0a[128 + hu], bga = b0a[256 + hu], boa = b0a[384 + hu];
    const float bdv = bdf[(w & 3) * 16 + l15];

    float c0s[4] = {0.f, 0.f, 0.f, 0.f};
    float c1s[4] = {0.f, 0.f, 0.f, 0.f};

    const int colx = tid & 63, rg = tid >> 6;

    __syncthreads();   // staging complete

    // =================== warm steps 0..49 (x input) ===================
    for (int step = 0; step < Tt; ++step) {
        const int p = step & 1, q = p ^ 1;
        short* a0p = a0b + p * A0SZ;  short* a0q = a0b + q * A0SZ;
        short* a1p = a1b + p * A1SZ;  short* a1q = a1b + q * A1SZ;

        float xv0, xv1;
        if (step < Tt - 1) {
            xv0 = x[(size_t)(row0 + rg)     * (Tt * Dd) + (step + 1) * Dd + colx];
            xv1 = x[(size_t)(row0 + rg + 8) * (Tt * Dd) + (step + 1) * Dd + colx];
        }

        // layer 0 (warm): A = [x | h0], K=192
        floatx4 acc[4];
        acc[0] = (floatx4){bi0,  bi0,  bi0,  bi0};
        acc[1] = (floatx4){bff0, bff0, bff0, bff0};
        acc[2] = (floatx4){bg0,  bg0,  bg0,  bg0};
        acc[3] = (floatx4){bo0,  bo0,  bo0,  bo0};
        #pragma unroll
        for (int kt = 0; kt < 6; ++kt) {
            short8 af = (kt < 2)
                ? *(const short8*)&a0p[l15 * K0S + kt * 32 + quad * 8]
                : *(const short8*)&a1q[l15 * K1P + (kt - 2) * 32 + quad * 8];
            #pragma unroll
            for (int g = 0; g < 4; ++g) {
                int pp = g * 6 + kt;
                short8 bfr = (pp < 16) ? *(const short8*)&w0l[((pp * 8 + w) << 9) + lane * 8]
                                       : W0R[pp - 16];
                acc[g] = __builtin_amdgcn_mfma_f32_16x16x32_bf16(af, bfr, acc[g], 0, 0, 0);
            }
        }

        // gates layer 0 -> h0' into a1[p] cols 0..127   (5 exp2 + 2 rcp form)
        #pragma unroll
        for (int r = 0; r < 4; ++r) {
            float A = EXP2(acc[0][r]), B = EXP2(acc[1][r]);
            float G = EXP2(acc[2][r]), O = EXP2(acc[3][r]);
            float oa = 1.f + A, og = 1.f + G, ob = 1.f + B, oo = 1.f + O;
            float d1 = oa * og;
            float num = fmaf(c0s[r], d1 * ob, 0.f);   // c*(d1*ob)? no — keep exact form below
            num = fmaf(c0s[r], d1, (1.f - G) * ob);
            float c = num * rcp_(d1 * ob);
            c0s[r] = c;
            float C2 = EXP2(c * KN2L2E);
            float h = (1.f - C2) * rcp_(oo * (1.f + C2));
            a1p[(quad * 4 + r) * K1P + hu] = f2bf(h);
        }

        if (step < Tt - 1) {
            a0q[rg * K0S + colx]       = f2bf(xv0);
            a0q[(rg + 8) * K0S + colx] = f2bf(xv1);
        }
        __syncthreads();   // C: h0' (and next-x) visible

        // layer 1: A = a1[p] = [h0' | h1(s-1)]
        acc[0] = (floatx4){bi1,  bi1,  bi1,  bi1};
        acc[1] = (floatx4){bff1, bff1, bff1, bff1};
        acc[2] = (floatx4){bg1,  bg1,  bg1,  bg1};
        acc[3] = (floatx4){bo1,  bo1,  bo1,  bo1};
        #pragma unroll
        for (int kt = 0; kt < 8; ++kt) {
            short8 af = *(const short8*)&a1p[l15 * K1P + kt * 32 + quad * 8];
            #pragma unroll
            for (int g = 0; g < 4; ++g)
                acc[g] = __builtin_amdgcn_mfma_f32_16x16x32_bf16(af, W1R[g][kt], acc[g], 0, 0, 0);
        }

        // gates layer 1 -> h1' into a1[q] cols 128..255
        #pragma unroll
        for (int r = 0; r < 4; ++r) {
            float A = EXP2(acc[0][r]), B = EXP2(acc[1][r]);
            float G = EXP2(acc[2][r]), O = EXP2(acc[3][r]);
            float oa = 1.f + A, og = 1.f + G, ob = 1.f + B, oo = 1.f + O;
            float d1 = oa * og;
            float num = fmaf(c1s[r], d1, (1.f - G) * ob);
            float c = num * rcp_(d1 * ob);
            c1s[r] = c;
            float C2 = EXP2(c * KN2L2E);
            float h = (1.f - C2) * rcp_(oo * (1.f + C2));
            a1q[(quad * 4 + r) * K1P + 128 + hu] = f2bf(h);
        }

        if (step == Tt - 1) __syncthreads();   // E: publish h1(49) for AR-L0(50)
    }

    // =================== AR steps 50..148 (fused L0, lazy dense) ===================
    for (int step = Tt; step < Tt + NOUT - 1; ++step) {
        const int p = step & 1, q = p ^ 1;
        short* a1p = a1b + p * A1SZ;  short* a1q = a1b + q * A1SZ;

        // layer 0 (AR): A = [h1(s-1) | h0(s-1)], K=256; weights [Wf; Wr0]
        // + lazy dense output for step s-1 sharing the h1 fragment reads
        floatx4 acc[4];
        acc[0] = (floatx4){bia, bia, bia, bia};
        acc[1] = (floatx4){bfa, bfa, bfa, bfa};
        acc[2] = (floatx4){bga, bga, bga, bga};
        acc[3] = (floatx4){boa, boa, boa, boa};
        floatx4 ad = (floatx4){bdv, bdv, bdv, bdv};
        #pragma unroll
        for (int kt = 0; kt < 4; ++kt) {
            short8 af = *(const short8*)&a1p[l15 * K1P + 128 + kt * 32 + quad * 8];  // h1(s-1)
            #pragma unroll
            for (int g = 0; g < 4; ++g)
                acc[g] = __builtin_amdgcn_mfma_f32_16x16x32_bf16(af, WfR[g * 4 + kt], acc[g], 0, 0, 0);
            if (w < 4)
                ad = __builtin_amdgcn_mfma_f32_16x16x32_bf16(af, WdR[kt], ad, 0, 0, 0);
        }
        #pragma unroll
        for (int kt = 4; kt < 8; ++kt) {
            short8 af = *(const short8*)&a1q[l15 * K1P + (kt - 4) * 32 + quad * 8];  // h0(s-1)
            #pragma unroll
            for (int g = 0; g < 4; ++g) {
                int pp = g * 6 + kt - 2;   // Wr0 rows: original kt' = kt-4+2
                short8 bfr = (pp < 16) ? *(const short8*)&w0l[((pp * 8 + w) << 9) + lane * 8]
                                       : W0R[pp - 16];
                acc[g] = __builtin_amdgcn_mfma_f32_16x16x32_bf16(af, bfr, acc[g], 0, 0, 0);
            }
        }

        // store pred(s-1) (output slot step-50), fire-and-forget
        if (w < 4) {
            int s = step - Tt;
            #pragma unroll
            for (int r = 0; r < 4; ++r)
                out[(size_t)(row0 + quad * 4 + r) * (NOUT * Dd) + s * Dd + w * 16 + l15] = ad[r];
        }

        // gates layer 0 -> h0(s) into a1[p] cols 0..127
        #pragma unroll
        for (int r = 0; r < 4; ++r) {
            float A = EXP2(acc[0][r]), B = EXP2(acc[1][r]);
            float G = EXP2(acc[2][r]), O = EXP2(acc[3][r]);
            float oa = 1.f + A, og = 1.f + G, ob = 1.f + B, oo = 1.f + O;
            float d1 = oa * og;
            float num = fmaf(c0s[r], d1, (1.f - G) * ob);
            float c = num * rcp_(d1 * ob);
            c0s[r] = c;
            float C2 = EXP2(c * KN2L2E);
            float h = (1.f - C2) * rcp_(oo * (1.f + C2));
            a1p[(quad * 4 + r) * K1P + hu] = f2bf(h);
        }
        __syncthreads();   // C: h0(s) visible

        // layer 1: A = a1[p] = [h0(s) | h1(s-1)]
        acc[0] = (floatx4){bi1,  bi1,  bi1,  bi1};
        acc[1] = (floatx4){bff1, bff1, bff1, bff1};
        acc[2] = (floatx4){bg1,  bg1,  bg1,  bg1};
        acc[3] = (floatx4){bo1,  bo1,  bo1,  bo1};
        #pragma unroll
        for (int kt = 0; kt < 8; ++kt) {
            short8 af = *(const short8*)&a1p[l15 * K1P + kt * 32 + quad * 8];
            #pragma unroll
            for (int g = 0; g < 4; ++g)
                acc[g] = __builtin_amdgcn_mfma_f32_16x16x32_bf16(af, W1R[g][kt], acc[g], 0, 0, 0);
        }

        // gates layer 1 -> h1(s) into a1[q] cols 128..255
        #pragma unroll
        for (int r = 0; r < 4; ++r) {
            float A = EXP2(acc[0][r]), B = EXP2(acc[1][r]);
            float G = EXP2(acc[2][r]), O = EXP2(acc[3][r]);
            float oa = 1.f + A, og = 1.f + G, ob = 1.f + B, oo = 1.f + O;
            float d1 = oa * og;
            float num = fmaf(c1s[r], d1, (1.f - G) * ob);
            float c = num * rcp_(d1 * ob);
            c1s[r] = c;
            float C2 = EXP2(c * KN2L2E);
            float h = (1.f - C2) * rcp_(oo * (1.f + C2));
            a1q[(quad * 4 + r) * K1P + 128 + hu] = f2bf(h);
        }
        __syncthreads();   // E: publish h1(s)
    }

    // epilogue: dense for h1(148) -> output slot 99
    if (w < 4) {
        const short* a1f = a1b + A1SZ;   // q(148) = buffer 1
        floatx4 ad = (floatx4){bdv, bdv, bdv, bdv};
        #pragma unroll
        for (int kt = 0; kt < 4; ++kt) {
            short8 af = *(const short8*)&a1f[l15 * K1P + 128 + kt * 32 + quad * 8];
            ad = __builtin_amdgcn_mfma_f32_16x16x32_bf16(af, WdR[kt], ad, 0, 0, 0);
        }
        #pragma unroll
        for (int r = 0; r < 4; ++r)
            out[(size_t)(row0 + quad * 4 + r) * (NOUT * Dd) + 99 * Dd + w * 16 + l15] = ad[r];
    }
}

extern "C" void kernel_launch(void* const* d_in, const int* in_sizes, int n_in,
                              void* d_out, int out_size, void* d_ws, size_t ws_size,
                              hipStream_t stream)
{
    (void)in_sizes; (void)n_in; (void)out_size; (void)ws_size;
    static_assert(SM_TOT <= 160 * 1024, "LDS budget");
    hipFuncSetAttribute(reinterpret_cast<const void*>(lstm_kernel),
                        hipFuncAttributeMaxDynamicSharedMemorySize, SM_TOT);
    prep_kernel<<<1191, 256, 0, stream>>>(
        (const float*)d_in[1], (const float*)d_in[2], (const float*)d_in[3],
        (const float*)d_in[4], (const float*)d_in[5], (const float*)d_in[6],
        (const float*)d_in[7], (const float*)d_in[8], (char*)d_ws);
    lstm_kernel<<<256, 512, SM_TOT, stream>>>(
        (const float*)d_in[0], (const char*)d_ws, (float*)d_out);
}